// Round 4
// baseline (122.255 us; speedup 1.0000x reference)
//
#include <hip/hip_runtime.h>

#define DK 256   // feature dim (K)
#define TT 1024  // T1 = T2
#define NB 16    // batch

typedef __attribute__((ext_vector_type(8))) short bf16x8;
typedef __attribute__((ext_vector_type(8))) unsigned short u16x8;
typedef __attribute__((ext_vector_type(4))) float f32x4;

// round-to-nearest-even fp32 -> bf16 (inputs are finite normals)
__device__ __forceinline__ unsigned short f2bf(float f) {
    unsigned int u = __float_as_uint(f);
    unsigned int r = 0x7fffu + ((u >> 16) & 1u);
    return (unsigned short)((u + r) >> 16);
}

// ---------------------------------------------------------------------------
// Fully fused: out[b,i,j] = sum_k bf16(x)[b,i,k]*bf16(w3*y)[b,j,k]
//                           + (x.w1)[b,i] + (y.w2)[b,j]
//
// One kernel, no workspace. Per block (jt,is,b):
//  1. Stage B-tile = bf16(w3 * y[128 j rows x 256 k]) into 64 KB LDS
//     (fp32 loads -> cvt -> ds_write_b128), computing ty = y.w2 inline.
//     XOR-swizzled 16B-chunk layout: chunk cg of row j at slot cg^(j&7)
//     -> MFMA fragment ds_read_b128 is 2-lane/bank max (free).
//  2. ONE barrier.
//  3. Barrier-free K-loop: each wave owns 64 i-rows, streams x fp32
//     global->VGPR (compiler-scheduled fine-grained vmcnt overlap),
//     converts to bf16 in-register, accumulates tx = x.w1 via fp32 FMA
//     on the side. 256 MFMA/wave into a 64x128 f32 accumulator.
//  4. Epilogue: quad-butterfly + shfl for tx, LDS for ty, fp32 stores.
//
// HBM: 128 MB in + 64 MB out = 192 MB (~30 us); x's 8x j-tile reuse is
// served by L3 (inputs 128 MB < 256 MB). VALU (cvt+fma) and MFMA both
// hide under the memory time.
// ---------------------------------------------------------------------------
__global__ __launch_bounds__(256, 2) void fused_kernel(
    const float* __restrict__ x, const float* __restrict__ y,
    const float* __restrict__ WS, float* __restrict__ out)
{
    __shared__ unsigned short Bs[128 * DK];   // 64 KB
    __shared__ float tys[128];

    const int tid  = threadIdx.x;
    const int lane = tid & 63;
    const int w    = tid >> 6;
    const int jt = blockIdx.x;    // j tile (0..7), 128 cols
    const int is = blockIdx.y;    // i slice (0..3), 256 rows
    const int b  = blockIdx.z;    // batch

    // ---- 1. stage B = bf16(w3*y), ty = y.w2   (thread t: row t>>1, half t&1)
    {
        const int j = tid >> 1;
        const int h = tid & 1;
        const float* gY  = y + ((size_t)b * TT + jt * 128 + j) * DK + h * 128;
        const float* w3p = WS + 2 * DK + h * 128;
        const float* w2p = WS + DK + h * 128;
        unsigned short* Brow = Bs + j * DK;
        float typ = 0.f;
        #pragma unroll
        for (int c = 0; c < 16; ++c) {
            const int d0 = c * 8;
            const float4 ya = *(const float4*)(gY + d0);
            const float4 yb = *(const float4*)(gY + d0 + 4);
            const float4 wa = *(const float4*)(w3p + d0);
            const float4 wb = *(const float4*)(w3p + d0 + 4);
            const float4 va = *(const float4*)(w2p + d0);
            const float4 vb = *(const float4*)(w2p + d0 + 4);
            typ += ya.x * va.x + ya.y * va.y + ya.z * va.z + ya.w * va.w
                 + yb.x * vb.x + yb.y * vb.y + yb.z * vb.z + yb.w * vb.w;
            u16x8 o;
            o[0] = f2bf(ya.x * wa.x); o[1] = f2bf(ya.y * wa.y);
            o[2] = f2bf(ya.z * wa.z); o[3] = f2bf(ya.w * wa.w);
            o[4] = f2bf(yb.x * wb.x); o[5] = f2bf(yb.y * wb.y);
            o[6] = f2bf(yb.z * wb.z); o[7] = f2bf(yb.w * wb.w);
            const int cg   = h * 16 + c;          // global 16B chunk index
            const int slot = cg ^ (j & 7);        // swizzled LDS slot
            *(u16x8*)(Brow + slot * 8) = o;
        }
        typ += __shfl_xor(typ, 1);
        if (h == 0) tys[j] = typ;
    }
    __syncthreads();                              // the ONLY barrier

    // ---- 3. barrier-free K-loop
    const int mfr  = lane & 15;
    const int quad = lane >> 4;
    const int i0   = is * 256 + w * 64;           // wave's 64-row i-base
    const float* gA = x + ((size_t)b * TT + i0) * DK;

    f32x4 acc[4][8];
    #pragma unroll
    for (int it = 0; it < 4; ++it)
        #pragma unroll
        for (int n = 0; n < 8; ++n)
            acc[it][n] = (f32x4){0.f, 0.f, 0.f, 0.f};
    float txp[4] = {0.f, 0.f, 0.f, 0.f};

    #pragma unroll
    for (int ks = 0; ks < 8; ++ks) {
        const float* w1p = WS + ks * 32 + quad * 8;
        const float4 w1a = *(const float4*)(w1p);
        const float4 w1b = *(const float4*)(w1p + 4);
        bf16x8 av[4];
        #pragma unroll
        for (int it = 0; it < 4; ++it) {
            const float* rp = gA + (size_t)(it * 16 + mfr) * DK
                              + ks * 32 + quad * 8;
            const float4 xa = *(const float4*)rp;
            const float4 xb = *(const float4*)(rp + 4);
            txp[it] += xa.x * w1a.x + xa.y * w1a.y + xa.z * w1a.z + xa.w * w1a.w
                     + xb.x * w1b.x + xb.y * w1b.y + xb.z * w1b.z + xb.w * w1b.w;
            bf16x8 a;
            a[0] = (short)f2bf(xa.x); a[1] = (short)f2bf(xa.y);
            a[2] = (short)f2bf(xa.z); a[3] = (short)f2bf(xa.w);
            a[4] = (short)f2bf(xb.x); a[5] = (short)f2bf(xb.y);
            a[6] = (short)f2bf(xb.z); a[7] = (short)f2bf(xb.w);
            av[it] = a;
        }
        #pragma unroll
        for (int n = 0; n < 8; ++n) {
            const int j    = n * 16 + mfr;
            const int slot = (ks * 4 + quad) ^ (j & 7);
            const bf16x8 bv = *(const bf16x8*)(Bs + j * DK + slot * 8);
            #pragma unroll
            for (int it = 0; it < 4; ++it)
                acc[it][n] = __builtin_amdgcn_mfma_f32_16x16x32_bf16(
                    av[it], bv, acc[it][n], 0, 0, 0);
        }
    }

    // ---- 4. epilogue: tx quad-reduction, + tx[i] + ty[j], fp32 stores
    #pragma unroll
    for (int it = 0; it < 4; ++it) {
        txp[it] += __shfl_xor(txp[it], 16);
        txp[it] += __shfl_xor(txp[it], 32);
        // now lane holds full tx for row i0 + it*16 + mfr
    }

    float tyv[8];
    #pragma unroll
    for (int n = 0; n < 8; ++n)
        tyv[n] = tys[n * 16 + mfr];

    float* outB = out + ((size_t)b << 20) + (size_t)i0 * TT + jt * 128;
    #pragma unroll
    for (int it = 0; it < 4; ++it) {
        #pragma unroll
        for (int r = 0; r < 4; ++r) {
            const int row = it * 16 + quad * 4 + r;
            // tx for this row lives at lanes with mfr == quad*4+r (any quad)
            const float trow = __shfl(txp[it], (lane & 48) | (quad * 4 + r));
            #pragma unroll
            for (int n = 0; n < 8; ++n)
                outB[(size_t)row * TT + n * 16 + mfr] =
                    acc[it][n][r] + trow + tyv[n];
        }
    }
}

extern "C" void kernel_launch(void* const* d_in, const int* in_sizes, int n_in,
                              void* d_out, int out_size, void* d_ws, size_t ws_size,
                              hipStream_t stream)
{
    const float* x  = (const float*)d_in[0];
    const float* y  = (const float*)d_in[1];
    const float* WS = (const float*)d_in[2];
    float* out = (float*)d_out;
    (void)d_ws; (void)ws_size;   // no workspace needed — fully fused

    fused_kernel<<<dim3(8, 4, NB), dim3(256), 0, stream>>>(x, y, WS, out);
}

// Round 5
// 109.623 us; speedup vs baseline: 1.1152x; 1.1152x over previous
//
#include <hip/hip_runtime.h>

#define DK 256   // feature dim (K)
#define TT 1024  // T1 = T2
#define NB 16    // batch

typedef __attribute__((ext_vector_type(8))) short bf16x8;
typedef __attribute__((ext_vector_type(8))) unsigned short u16x8;
typedef __attribute__((ext_vector_type(4))) float f32x4;

// round-to-nearest-even fp32 -> bf16 (inputs are finite normals)
__device__ __forceinline__ unsigned short f2bf(float f) {
    unsigned int u = __float_as_uint(f);
    unsigned int r = 0x7fffu + ((u >> 16) & 1u);
    return (unsigned short)((u + r) >> 16);
}

// ---------------------------------------------------------------------------
// Fully fused: out[b,i,j] = sum_k bf16(x)[b,i,k]*bf16(w3*y)[b,j,k]
//                           + (x.w1)[b,i] + (y.w2)[b,j]
//
// R5 changes vs R4 (which was latency-bound: 8 waves/CU, hbm 2.5 TB/s):
//  * 512-thread blocks (8 waves) -> 16 waves/CU at the same 64 KB LDS.
//    Each wave owns 32 i-rows (acc[2][8] = 64 VGPRs).
//  * Contiguous-chunk staging: thread t stages 16B chunk (it*512+t);
//    a wave covers 2 full rows -> fully coalesced global reads AND
//    conflict-free XOR-swizzled LDS writes (8 distinct slots per 8-lane
//    phase). ty = y.w2 reduced via 32-lane shfl_xor.
//  * XCD-locality block-id swizzle: blocks sharing an x-slice (same is,b;
//    jt 0..7 at ids +64 apart) and blocks sharing a y-tile (same b,jt;
//    is 0..3 at ids +16 apart) keep id mod 8 constant -> same XCD under
//    round-robin dispatch -> x/y re-reads served from that XCD's L2
//    (~4 MB working set/XCD).
// ---------------------------------------------------------------------------
__global__ __launch_bounds__(512, 4) void fused_kernel(
    const float* __restrict__ x, const float* __restrict__ y,
    const float* __restrict__ WS, float* __restrict__ out)
{
    __shared__ unsigned short Bs[128 * DK];   // 64 KB
    __shared__ float tys[128];

    const int tid  = threadIdx.x;
    const int lane = tid & 63;
    const int w    = tid >> 6;                // wave 0..7

    // XCD-locality decode: id%8 constant across the jt group and the is group
    const int id = blockIdx.x;                // 0..511
    const int b  = id & 15;                   // batch
    const int is = (id >> 4) & 3;             // i slice (0..3), 256 rows
    const int jt = id >> 6;                   // j tile (0..7), 128 cols

    // ---- 1. stage B = bf16(w3*y) (XOR-swizzled), ty = y.w2
    {
        const float* gY0 = y + ((size_t)b * TT + jt * 128) * DK;
        #pragma unroll
        for (int it = 0; it < 8; ++it) {
            const int g = it * 512 + tid;     // global 16B chunk 0..4095
            const int j = g >> 5;             // local row 0..127
            const int c = g & 31;             // chunk within row
            const float* gY  = gY0 + (size_t)j * DK + c * 8;
            const float* w3p = WS + 2 * DK + c * 8;
            const float* w2p = WS + DK + c * 8;
            const float4 ya = *(const float4*)(gY);
            const float4 yb = *(const float4*)(gY + 4);
            const float4 wa = *(const float4*)(w3p);
            const float4 wb = *(const float4*)(w3p + 4);
            const float4 va = *(const float4*)(w2p);
            const float4 vb = *(const float4*)(w2p + 4);
            float p = ya.x * va.x + ya.y * va.y + ya.z * va.z + ya.w * va.w
                    + yb.x * vb.x + yb.y * vb.y + yb.z * vb.z + yb.w * vb.w;
            u16x8 o;
            o[0] = f2bf(ya.x * wa.x); o[1] = f2bf(ya.y * wa.y);
            o[2] = f2bf(ya.z * wa.z); o[3] = f2bf(ya.w * wa.w);
            o[4] = f2bf(yb.x * wb.x); o[5] = f2bf(yb.y * wb.y);
            o[6] = f2bf(yb.z * wb.z); o[7] = f2bf(yb.w * wb.w);
            const int slot = c ^ (j & 7);
            *(u16x8*)(Bs + j * DK + slot * 8) = o;
            // reduce p across the 32 lanes sharing row j
            p += __shfl_xor(p, 1);
            p += __shfl_xor(p, 2);
            p += __shfl_xor(p, 4);
            p += __shfl_xor(p, 8);
            p += __shfl_xor(p, 16);
            if ((tid & 31) == 0) tys[j] = p;
        }
    }
    __syncthreads();                          // the ONLY barrier

    // ---- 2. barrier-free K-loop: wave owns 32 i-rows
    const int mfr  = lane & 15;
    const int quad = lane >> 4;
    const int i0   = is * 256 + w * 32;
    const float* gA = x + ((size_t)b * TT + i0) * DK;

    f32x4 acc[2][8];
    #pragma unroll
    for (int it = 0; it < 2; ++it)
        #pragma unroll
        for (int n = 0; n < 8; ++n)
            acc[it][n] = (f32x4){0.f, 0.f, 0.f, 0.f};
    float txp[2] = {0.f, 0.f};

    #pragma unroll
    for (int ks = 0; ks < 8; ++ks) {
        const float* w1p = WS + ks * 32 + quad * 8;
        const float4 w1a = *(const float4*)(w1p);
        const float4 w1b = *(const float4*)(w1p + 4);
        bf16x8 av[2];
        #pragma unroll
        for (int it = 0; it < 2; ++it) {
            const float* rp = gA + (size_t)(it * 16 + mfr) * DK
                              + ks * 32 + quad * 8;
            const float4 xa = *(const float4*)rp;
            const float4 xb = *(const float4*)(rp + 4);
            txp[it] += xa.x * w1a.x + xa.y * w1a.y + xa.z * w1a.z + xa.w * w1a.w
                     + xb.x * w1b.x + xb.y * w1b.y + xb.z * w1b.z + xb.w * w1b.w;
            bf16x8 a;
            a[0] = (short)f2bf(xa.x); a[1] = (short)f2bf(xa.y);
            a[2] = (short)f2bf(xa.z); a[3] = (short)f2bf(xa.w);
            a[4] = (short)f2bf(xb.x); a[5] = (short)f2bf(xb.y);
            a[6] = (short)f2bf(xb.z); a[7] = (short)f2bf(xb.w);
            av[it] = a;
        }
        #pragma unroll
        for (int n = 0; n < 8; ++n) {
            const int j    = n * 16 + mfr;
            const int slot = (ks * 4 + quad) ^ (j & 7);
            const bf16x8 bv = *(const bf16x8*)(Bs + j * DK + slot * 8);
            #pragma unroll
            for (int it = 0; it < 2; ++it)
                acc[it][n] = __builtin_amdgcn_mfma_f32_16x16x32_bf16(
                    av[it], bv, acc[it][n], 0, 0, 0);
        }
    }

    // ---- 3. epilogue: tx quad-reduction, + tx[i] + ty[j], fp32 stores
    #pragma unroll
    for (int it = 0; it < 2; ++it) {
        txp[it] += __shfl_xor(txp[it], 16);
        txp[it] += __shfl_xor(txp[it], 32);
        // lane now holds full tx for row i0 + it*16 + mfr
    }

    float tyv[8];
    #pragma unroll
    for (int n = 0; n < 8; ++n)
        tyv[n] = tys[n * 16 + mfr];

    float* outB = out + ((size_t)b << 20) + (size_t)i0 * TT + jt * 128;
    #pragma unroll
    for (int it = 0; it < 2; ++it) {
        #pragma unroll
        for (int r = 0; r < 4; ++r) {
            const int row = it * 16 + quad * 4 + r;
            // tx for this row lives at lanes with mfr == quad*4+r (any quad)
            const float trow = __shfl(txp[it], (lane & 48) | (quad * 4 + r));
            #pragma unroll
            for (int n = 0; n < 8; ++n)
                outB[(size_t)row * TT + n * 16 + mfr] =
                    acc[it][n][r] + trow + tyv[n];
        }
    }
}

extern "C" void kernel_launch(void* const* d_in, const int* in_sizes, int n_in,
                              void* d_out, int out_size, void* d_ws, size_t ws_size,
                              hipStream_t stream)
{
    const float* x  = (const float*)d_in[0];
    const float* y  = (const float*)d_in[1];
    const float* WS = (const float*)d_in[2];
    float* out = (float*)d_out;
    (void)d_ws; (void)ws_size;   // no workspace needed — fully fused

    fused_kernel<<<dim3(512), dim3(512), 0, stream>>>(x, y, WS, out);
}